// Round 5
// baseline (260.967 us; speedup 1.0000x reference)
//
#include <hip/hip_runtime.h>
#include <hip/hip_bf16.h>
#include <stdint.h>

typedef __attribute__((ext_vector_type(8))) short short8;   // 8 bf16 (4 VGPRs) MFMA A/B frag
typedef __attribute__((ext_vector_type(4))) float f32x4;    // MFMA C/D frag

__device__ __forceinline__ float softplus_f(float x) {
    return (x > 0.f) ? (x + log1pf(expf(-x))) : log1pf(expf(x));
}

// mode 0: plain cast; mode 1: column-monotone (cols 0..3 -> +softplus, 4..7 -> -softplus, rest raw, 256 cols);
// mode 2: softplus everywhere
__global__ void xform_kernel(const float* __restrict__ src, __hip_bfloat16* __restrict__ dst,
                             int n4, int mode) {
    int i = blockIdx.x * blockDim.x + threadIdx.x;
    if (i >= n4) return;
    float4 v = reinterpret_cast<const float4*>(src)[i];
    float r[4] = {v.x, v.y, v.z, v.w};
    int base = i << 2;
#pragma unroll
    for (int j = 0; j < 4; ++j) {
        float x = r[j];
        float y = x;
        if (mode == 2) {
            y = softplus_f(x);
        } else if (mode == 1) {
            int col = (base + j) & 255;
            if (col < 8) {
                float s = softplus_f(x);
                y = (col < 4) ? s : -s;
            }
        }
        dst[base + j] = __float2bfloat16(y);
    }
}

#define GLOAD16(src, dst)                                                                  \
    __builtin_amdgcn_global_load_lds((const __attribute__((address_space(1))) void*)(src), \
                                     (__attribute__((address_space(3))) void*)(dst), 16, 0, 0)

// Fused ICNN layer. Tile BM=128 x BN=256, 8 waves (2M x 4N), per-wave 64x64 (acc[4][4]).
// BK=64, 3 LDS buffers (144KB). m201-style phased schedule:
//   per K-step, 2 phases of {8 ds_read_b128 | issue 3 DMA loads of stage(s+2) |
//   s_barrier | lgkmcnt(0)+sched_barrier | setprio(1) 16xMFMA setprio(0)},
//   plus ONE counted vmcnt(6)+s_barrier at step top (per-wave vmcnt published by barrier).
// MFMA execution drains past the barriers, so next phase's LDS reads overlap it.
// Step map (HAS_U): 0-3 xf@Wut^T (relu'd at step 3), 4-7 xc@Wc^T, 8-11 xf@Wu^T, 12-27 z@U^T.
template<bool HAS_U, bool WRITE_F32>
__global__ __launch_bounds__(512, 2)
void icnn_layer_kernel(const short* __restrict__ xc, const short* __restrict__ xf,
                       const short* __restrict__ zin,
                       const short* __restrict__ Wc, const short* __restrict__ Wu,
                       const short* __restrict__ Wut, const short* __restrict__ U,
                       const float* __restrict__ bc, const float* __restrict__ bu,
                       const float* __restrict__ but,
                       __hip_bfloat16* __restrict__ zout, float* __restrict__ fout)
{
    __shared__ short As[3][128 * 64];   // 16KB per buffer
    __shared__ short Bs[3][256 * 64];   // 32KB per buffer; total 144KB
    const int t = threadIdx.x;          // 0..511
    const int lane = t & 63;
    const int wid = t >> 6;             // 0..7
    const int wr = wid >> 2;            // 0..1 (64-row slice of 128)
    const int wc = wid & 3;             // 0..3 (64-col slice of 256)
    const int l15 = lane & 15, l4 = lane >> 4;
    const int swz = l15 & 7;            // == row&7 for every fragment row this lane reads
    const int brow = blockIdx.x * 128;
    const int bcol = blockIdx.y * 256;

    constexpr int NSTEP = HAS_U ? 28 : 12;

    f32x4 acc[4][4];
#pragma unroll
    for (int m = 0; m < 4; ++m)
#pragma unroll
        for (int n = 0; n < 4; ++n) acc[m][n] = (f32x4){0.f, 0.f, 0.f, 0.f};

    // hoisted u-path bias
    float bt[4];
#pragma unroll
    for (int n = 0; n < 4; ++n) bt[n] = but[bcol + wc * 64 + n * 16 + l15];

    // resolve operands for step s; ld given as shift (256 -> 8, 1024 -> 10)
    auto seg = [&](int s, const short*& A, int& lsa, const short*& B, int& lsb, int& k0) {
        if (s < 4)       { A = xf;  lsa = 8;  B = Wut; lsb = 8;  k0 = s * 64; }
        else if (s < 8)  { A = xc;  lsa = 8;  B = Wc;  lsb = 8;  k0 = (s - 4) * 64; }
        else if (s < 12) { A = xf;  lsa = 8;  B = Wu;  lsb = 8;  k0 = (s - 8) * 64; }
        else             { A = zin; lsa = 10; B = U;   lsb = 10; k0 = (s - 12) * 64; }
    };

    // half-stage for step s into buffer sel: part 0 = A tile (2 loads) + B chunk 0 (1 load);
    // part 1 = B chunks 1..3 (3 loads). LDS dest linear, source column-chunk XOR-swizzled.
    auto stage_part = [&](int sel, int s, int part) {
        const short *A, *B; int lsa, lsb, k0;
        seg(s, A, lsa, B, lsb, k0);
        if (part == 0) {
#pragma unroll
            for (int it = 0; it < 2; ++it) {
                int c = it * 512 + t;
                int row = c >> 3;                 // 8 chunks per 64-elem row
                int js = (c & 7) ^ (row & 7);     // inverse swizzle on source
                GLOAD16(A + (((size_t)(brow + row)) << lsa) + k0 + js * 8, &As[sel][c * 8]);
            }
            {
                int c = t;
                int row = c >> 3;
                int js = (c & 7) ^ (row & 7);
                GLOAD16(B + (((size_t)(bcol + row)) << lsb) + k0 + js * 8, &Bs[sel][c * 8]);
            }
        } else {
#pragma unroll
            for (int it = 1; it < 4; ++it) {
                int c = it * 512 + t;
                int row = c >> 3;
                int js = (c & 7) ^ (row & 7);
                GLOAD16(B + (((size_t)(bcol + row)) << lsb) + k0 + js * 8, &Bs[sel][c * 8]);
            }
        }
    };

    // ---- prologue: 2 stages in flight (12 loads/thread) ----
    stage_part(0, 0, 0); stage_part(0, 0, 1);
    stage_part(1, 1, 0); stage_part(1, 1, 1);

    // ---- main loop ----
    for (int s = 0; s < NSTEP; ++s) {
        // publish stage(s): each wave waits its own 6 stage(s) loads (stage(s+1)'s 6 stay
        // in flight), then the barrier makes ALL waves' landings visible.
        if (s == NSTEP - 1) {
            asm volatile("s_waitcnt vmcnt(0)" ::: "memory");
        } else {
            asm volatile("s_waitcnt vmcnt(6)" ::: "memory");
        }
        __builtin_amdgcn_s_barrier();
        __builtin_amdgcn_sched_barrier(0);

        const int sel = s % 3;
        const short* Asel = &As[sel][0];
        const short* Bsel = &Bs[sel][0];
        const bool doStage = (s + 2 < NSTEP);
        const int s2sel = (s + 2) % 3;

#pragma unroll
        for (int kk = 0; kk < 2; ++kk) {
            // phase kk: read 8 fragments, issue half of stage(s+2), sync, 16 MFMA
            short8 a[4], b[4];
            const int joff = ((kk * 4 + l4) ^ swz) << 3;   // swizzled column offset (shorts)
#pragma unroll
            for (int m = 0; m < 4; ++m)
                a[m] = *(const short8*)&Asel[((wr * 64 + m * 16 + l15) << 6) + joff];
#pragma unroll
            for (int n = 0; n < 4; ++n)
                b[n] = *(const short8*)&Bsel[((wc * 64 + n * 16 + l15) << 6) + joff];

            if (doStage) stage_part(s2sel, s + 2, kk);

            __builtin_amdgcn_s_barrier();                        // all waves issued reads+stage
            asm volatile("s_waitcnt lgkmcnt(0)" ::: "memory");   // my fragments landed
            __builtin_amdgcn_sched_barrier(0);                   // rule 18: keep MFMA below wait

            __builtin_amdgcn_s_setprio(1);
#pragma unroll
            for (int m = 0; m < 4; ++m)
#pragma unroll
                for (int n = 0; n < 4; ++n)
                    acc[m][n] = __builtin_amdgcn_mfma_f32_16x16x32_bf16(a[m], b[n], acc[m][n], 0, 0, 0);
            __builtin_amdgcn_s_setprio(0);
        }

        if (s == 3) {
            // u = relu(xf@Wut^T + but); MFMA accumulates the remaining paths on top
#pragma unroll
            for (int n = 0; n < 4; ++n)
#pragma unroll
                for (int m = 0; m < 4; ++m)
#pragma unroll
                    for (int v = 0; v < 4; ++v)
                        acc[m][n][v] = fmaxf(acc[m][n][v] + bt[n], 0.f);
        }
    }

    // ---- epilogue: + (bc + bu), relu, store ----
#pragma unroll
    for (int n = 0; n < 4; ++n) {
        int col = bcol + wc * 64 + n * 16 + l15;
        float bb = bc[col] + bu[col];
#pragma unroll
        for (int m = 0; m < 4; ++m) {
            int row = brow + wr * 64 + m * 16 + l4 * 4;
#pragma unroll
            for (int v = 0; v < 4; ++v) {
                float val = fmaxf(acc[m][n][v] + bb, 0.f);
                if constexpr (WRITE_F32) {
                    fout[(size_t)(row + v) * 1024 + col] = val;
                } else {
                    zout[(size_t)(row + v) * 1024 + col] = __float2bfloat16(val);
                }
            }
        }
    }
}

extern "C" void kernel_launch(void* const* d_in, const int* in_sizes, int n_in,
                              void* d_out, int out_size, void* d_ws, size_t ws_size,
                              hipStream_t stream)
{
    const float* xc    = (const float*)d_in[0];
    const float* xf    = (const float*)d_in[1];
    const float* Wc_w  = (const float*)d_in[2];
    const float* Wc_b  = (const float*)d_in[3];
    const float* Wu_w  = (const float*)d_in[4];
    const float* Wu_b  = (const float*)d_in[5];
    const float* Wut_w = (const float*)d_in[6];
    const float* Wut_b = (const float*)d_in[7];
    const float* raw_U = (const float*)d_in[8];

    // workspace layout (bf16 buffers), ~36 MB total
    short* p = (short*)d_ws;
    short* xc_bf  = p; p += 8192 * 256;
    short* xf_bf  = p; p += 8192 * 256;
    short* Wc_bf  = p; p += 4 * 1024 * 256;
    short* Wu_bf  = p; p += 4 * 1024 * 256;
    short* Wut_bf = p; p += 4 * 1024 * 256;
    short* U_bf   = p; p += 3 * 1024 * 1024;
    short* z_a    = p; p += 8192 * 1024;
    // z_b lives in d_out (bf16 scratch); layer 3 fully overwrites d_out with fp32 result.
    short* z_b = (short*)d_out;

    dim3 tb256(256);
    xform_kernel<<<dim3(2048), tb256, 0, stream>>>(xc,    (__hip_bfloat16*)xc_bf,  8192 * 256 / 4, 0);
    xform_kernel<<<dim3(2048), tb256, 0, stream>>>(xf,    (__hip_bfloat16*)xf_bf,  8192 * 256 / 4, 0);
    xform_kernel<<<dim3(1024), tb256, 0, stream>>>(Wc_w,  (__hip_bfloat16*)Wc_bf,  4 * 1024 * 256 / 4, 1);
    xform_kernel<<<dim3(1024), tb256, 0, stream>>>(Wu_w,  (__hip_bfloat16*)Wu_bf,  4 * 1024 * 256 / 4, 1);
    xform_kernel<<<dim3(1024), tb256, 0, stream>>>(Wut_w, (__hip_bfloat16*)Wut_bf, 4 * 1024 * 256 / 4, 1);
    xform_kernel<<<dim3(3072), tb256, 0, stream>>>(raw_U, (__hip_bfloat16*)U_bf,   3 * 1024 * 1024 / 4, 2);

    dim3 tb(512);
    dim3 grid(8192 / 128, 1024 / 256);   // 64 x 4 = 256 blocks = 1/CU
    const int WS = 1024 * 256;
    const int US = 1024 * 1024;

    // layer 0 (no recurrence) -> z_a
    icnn_layer_kernel<false, false><<<grid, tb, 0, stream>>>(
        xc_bf, xf_bf, nullptr, Wc_bf, Wu_bf, Wut_bf, nullptr,
        Wc_b, Wu_b, Wut_b, (__hip_bfloat16*)z_a, nullptr);
    // layer 1 -> z_b (in d_out)
    icnn_layer_kernel<true, false><<<grid, tb, 0, stream>>>(
        xc_bf, xf_bf, z_a, Wc_bf + WS, Wu_bf + WS, Wut_bf + WS, U_bf,
        Wc_b + 1024, Wu_b + 1024, Wut_b + 1024, (__hip_bfloat16*)z_b, nullptr);
    // layer 2 -> z_a
    icnn_layer_kernel<true, false><<<grid, tb, 0, stream>>>(
        xc_bf, xf_bf, z_b, Wc_bf + 2 * WS, Wu_bf + 2 * WS, Wut_bf + 2 * WS, U_bf + US,
        Wc_b + 2048, Wu_b + 2048, Wut_b + 2048, (__hip_bfloat16*)z_a, nullptr);
    // layer 3 -> fp32 d_out
    icnn_layer_kernel<true, true><<<grid, tb, 0, stream>>>(
        xc_bf, xf_bf, z_a, Wc_bf + 3 * WS, Wu_bf + 3 * WS, Wut_bf + 3 * WS, U_bf + 2 * US,
        Wc_b + 3072, Wu_b + 3072, Wut_b + 3072, nullptr, (float*)d_out);
}

// Round 6
// 201.645 us; speedup vs baseline: 1.2942x; 1.2942x over previous
//
#include <hip/hip_runtime.h>
#include <hip/hip_bf16.h>
#include <stdint.h>

typedef __attribute__((ext_vector_type(8))) short short8;   // 8 bf16 (4 VGPRs) MFMA A/B frag
typedef __attribute__((ext_vector_type(4))) float f32x4;    // MFMA C/D frag

__device__ __forceinline__ float softplus_f(float x) {
    return (x > 0.f) ? (x + log1pf(expf(-x))) : log1pf(expf(x));
}

// mode 0: plain cast; mode 1: column-monotone (cols 0..3 -> +softplus, 4..7 -> -softplus, rest raw, 256 cols);
// mode 2: softplus everywhere
__global__ void xform_kernel(const float* __restrict__ src, __hip_bfloat16* __restrict__ dst,
                             int n4, int mode) {
    int i = blockIdx.x * blockDim.x + threadIdx.x;
    if (i >= n4) return;
    float4 v = reinterpret_cast<const float4*>(src)[i];
    float r[4] = {v.x, v.y, v.z, v.w};
    int base = i << 2;
#pragma unroll
    for (int j = 0; j < 4; ++j) {
        float x = r[j];
        float y = x;
        if (mode == 2) {
            y = softplus_f(x);
        } else if (mode == 1) {
            int col = (base + j) & 255;
            if (col < 8) {
                float s = softplus_f(x);
                y = (col < 4) ? s : -s;
            }
        }
        dst[base + j] = __float2bfloat16(y);
    }
}

#define GLOAD16(src, dst)                                                                  \
    __builtin_amdgcn_global_load_lds((const __attribute__((address_space(1))) void*)(src), \
                                     (__attribute__((address_space(3))) void*)(dst), 16, 0, 0)

// Fused ICNN layer. Tile BM=128 x BN=256, 8 waves (2M x 4N), per-wave 64x64 (acc[4][4]).
// BK=64, 3 LDS buffers (144KB). Register-double-buffered fragments (round-6 structure):
// per iter: vmcnt(0) [stage(s+1), issued a FULL iter earlier] -> barrier ->
//   issue stage(s+2) -> ds_read (s,kk1) -> MFMA (s,kk0) [regs from prev iter, no stall]
//   -> ds_read (s+1,kk0) -> MFMA (s,kk1).
// Every ds_read group is covered by an independent MFMA cluster; one barrier per step.
// Step map (HAS_U): 0-3 xf@Wut^T (relu'd at step 3), 4-7 xc@Wc^T, 8-11 xf@Wu^T, 12-27 z@U^T.
template<bool HAS_U, bool WRITE_F32>
__global__ __launch_bounds__(512, 2)
void icnn_layer_kernel(const short* __restrict__ xc, const short* __restrict__ xf,
                       const short* __restrict__ zin,
                       const short* __restrict__ Wc, const short* __restrict__ Wu,
                       const short* __restrict__ Wut, const short* __restrict__ U,
                       const float* __restrict__ bc, const float* __restrict__ bu,
                       const float* __restrict__ but,
                       __hip_bfloat16* __restrict__ zout, float* __restrict__ fout)
{
    __shared__ short As[3][128 * 64];   // 16KB per buffer
    __shared__ short Bs[3][256 * 64];   // 32KB per buffer; total 144KB
    const int t = threadIdx.x;          // 0..511
    const int lane = t & 63;
    const int wid = t >> 6;             // 0..7
    const int wr = wid >> 2;            // 0..1 (64-row slice of 128)
    const int wc = wid & 3;             // 0..3 (64-col slice of 256)
    const int l15 = lane & 15, l4 = lane >> 4;
    const int swz = l15 & 7;            // == row&7 for every fragment row this lane reads
    const int brow = blockIdx.x * 128;
    const int bcol = blockIdx.y * 256;

    constexpr int NSTEP = HAS_U ? 28 : 12;

    f32x4 acc[4][4];
#pragma unroll
    for (int m = 0; m < 4; ++m)
#pragma unroll
        for (int n = 0; n < 4; ++n) acc[m][n] = (f32x4){0.f, 0.f, 0.f, 0.f};

    // hoisted u-path bias
    float bt[4];
#pragma unroll
    for (int n = 0; n < 4; ++n) bt[n] = but[bcol + wc * 64 + n * 16 + l15];

    // resolve operands for step s; ld given as shift (256 -> 8, 1024 -> 10)
    auto seg = [&](int s, const short*& A, int& lsa, const short*& B, int& lsb, int& k0) {
        if (s < 4)       { A = xf;  lsa = 8;  B = Wut; lsb = 8;  k0 = s * 64; }
        else if (s < 8)  { A = xc;  lsa = 8;  B = Wc;  lsb = 8;  k0 = (s - 4) * 64; }
        else if (s < 12) { A = xf;  lsa = 8;  B = Wu;  lsb = 8;  k0 = (s - 8) * 64; }
        else             { A = zin; lsa = 10; B = U;   lsb = 10; k0 = (s - 12) * 64; }
    };

    // stage tile for step s into buffer sel; LDS dest linear, source column-chunk XOR-swizzled
    auto stage = [&](int sel, int s) {
        const short *A, *B; int lsa, lsb, k0;
        seg(s, A, lsa, B, lsb, k0);
        short* Ad = &As[sel][0];
        short* Bd = &Bs[sel][0];
#pragma unroll
        for (int it = 0; it < 2; ++it) {
            int c = it * 512 + t;
            int row = c >> 3;                 // 8 chunks per 64-elem row
            int js = (c & 7) ^ (row & 7);     // inverse swizzle on source
            GLOAD16(A + (((size_t)(brow + row)) << lsa) + k0 + js * 8, Ad + c * 8);
        }
#pragma unroll
        for (int it = 0; it < 4; ++it) {
            int c = it * 512 + t;
            int row = c >> 3;
            int js = (c & 7) ^ (row & 7);
            GLOAD16(B + (((size_t)(bcol + row)) << lsb) + k0 + js * 8, Bd + c * 8);
        }
    };

    // read 8 fragments (one K=32 half of a step) into a register slot
    auto read_frags = [&](int sel, int kk, short8 (&a)[4], short8 (&b)[4]) {
        const short* Asel = &As[sel][0];
        const short* Bsel = &Bs[sel][0];
        const int joff = ((kk * 4 + l4) ^ swz) << 3;   // swizzled column offset (shorts)
#pragma unroll
        for (int m = 0; m < 4; ++m)
            a[m] = *(const short8*)&Asel[((wr * 64 + m * 16 + l15) << 6) + joff];
#pragma unroll
        for (int n = 0; n < 4; ++n)
            b[n] = *(const short8*)&Bsel[((wc * 64 + n * 16 + l15) << 6) + joff];
    };

    auto mfma16 = [&](short8 (&a)[4], short8 (&b)[4]) {
        __builtin_amdgcn_s_setprio(1);
#pragma unroll
        for (int m = 0; m < 4; ++m)
#pragma unroll
            for (int n = 0; n < 4; ++n)
                acc[m][n] = __builtin_amdgcn_mfma_f32_16x16x32_bf16(a[m], b[n], acc[m][n], 0, 0, 0);
        __builtin_amdgcn_s_setprio(0);
    };

    short8 aA[4], bA[4];   // slot A: (s, kk0) fragments, filled one iteration ahead
    short8 aB[4], bB[4];   // slot B: (s, kk1) fragments, filled in-iteration

    // ---- prologue: 2 stages in flight; cold-start full drain (once) ----
    stage(0, 0);
    stage(1, 1);
    asm volatile("s_waitcnt vmcnt(0)" ::: "memory");
    __builtin_amdgcn_s_barrier();
    read_frags(0, 0, aA, bA);

    // ---- main loop: ONE barrier + ONE vmcnt per step; reads covered by independent MFMA ----
    for (int s = 0; s < NSTEP; ++s) {
        if (s > 0) {
            // outstanding here: only stage(s+1)'s 6 loads, issued a FULL iteration ago
            asm volatile("s_waitcnt vmcnt(0)" ::: "memory");
            __builtin_amdgcn_s_barrier();
        }
        if (s + 2 < NSTEP) stage((s + 2) % 3, s + 2);

        read_frags(s % 3, 1, aB, bB);          // (s, kk1); buffer ready since previous iter
        __builtin_amdgcn_sched_barrier(0);     // pin read+stage issue before the MFMA cluster
        mfma16(aA, bA);                        // (s, kk0): regs loaded last iter -> no stall

        if (s + 1 < NSTEP) {
            read_frags((s + 1) % 3, 0, aA, bA);  // (s+1, kk0); buffer published by this barrier
            __builtin_amdgcn_sched_barrier(0);
        }
        mfma16(aB, bB);                        // (s, kk1): reads covered by previous cluster

        if (s == 3) {
            // u = relu(xf@Wut^T + but); MFMA accumulates the remaining paths on top
#pragma unroll
            for (int n = 0; n < 4; ++n)
#pragma unroll
                for (int m = 0; m < 4; ++m)
#pragma unroll
                    for (int v = 0; v < 4; ++v)
                        acc[m][n][v] = fmaxf(acc[m][n][v] + bt[n], 0.f);
        }
    }

    // ---- epilogue: + (bc + bu), relu, store ----
#pragma unroll
    for (int n = 0; n < 4; ++n) {
        int col = bcol + wc * 64 + n * 16 + l15;
        float bb = bc[col] + bu[col];
#pragma unroll
        for (int m = 0; m < 4; ++m) {
            int row = brow + wr * 64 + m * 16 + l4 * 4;
#pragma unroll
            for (int v = 0; v < 4; ++v) {
                float val = fmaxf(acc[m][n][v] + bb, 0.f);
                if constexpr (WRITE_F32) {
                    fout[(size_t)(row + v) * 1024 + col] = val;
                } else {
                    zout[(size_t)(row + v) * 1024 + col] = __float2bfloat16(val);
                }
            }
        }
    }
}

extern "C" void kernel_launch(void* const* d_in, const int* in_sizes, int n_in,
                              void* d_out, int out_size, void* d_ws, size_t ws_size,
                              hipStream_t stream)
{
    const float* xc    = (const float*)d_in[0];
    const float* xf    = (const float*)d_in[1];
    const float* Wc_w  = (const float*)d_in[2];
    const float* Wc_b  = (const float*)d_in[3];
    const float* Wu_w  = (const float*)d_in[4];
    const float* Wu_b  = (const float*)d_in[5];
    const float* Wut_w = (const float*)d_in[6];
    const float* Wut_b = (const float*)d_in[7];
    const float* raw_U = (const float*)d_in[8];

    // workspace layout (bf16 buffers), ~36 MB total
    short* p = (short*)d_ws;
    short* xc_bf  = p; p += 8192 * 256;
    short* xf_bf  = p; p += 8192 * 256;
    short* Wc_bf  = p; p += 4 * 1024 * 256;
    short* Wu_bf  = p; p += 4 * 1024 * 256;
    short* Wut_bf = p; p += 4 * 1024 * 256;
    short* U_bf   = p; p += 3 * 1024 * 1024;
    short* z_a    = p; p += 8192 * 1024;
    // z_b lives in d_out (bf16 scratch); layer 3 fully overwrites d_out with fp32 result.
    short* z_b = (short*)d_out;

    dim3 tb256(256);
    xform_kernel<<<dim3(2048), tb256, 0, stream>>>(xc,    (__hip_bfloat16*)xc_bf,  8192 * 256 / 4, 0);
    xform_kernel<<<dim3(2048), tb256, 0, stream>>>(xf,    (__hip_bfloat16*)xf_bf,  8192 * 256 / 4, 0);
    xform_kernel<<<dim3(1024), tb256, 0, stream>>>(Wc_w,  (__hip_bfloat16*)Wc_bf,  4 * 1024 * 256 / 4, 1);
    xform_kernel<<<dim3(1024), tb256, 0, stream>>>(Wu_w,  (__hip_bfloat16*)Wu_bf,  4 * 1024 * 256 / 4, 1);
    xform_kernel<<<dim3(1024), tb256, 0, stream>>>(Wut_w, (__hip_bfloat16*)Wut_bf, 4 * 1024 * 256 / 4, 1);
    xform_kernel<<<dim3(3072), tb256, 0, stream>>>(raw_U, (__hip_bfloat16*)U_bf,   3 * 1024 * 1024 / 4, 2);

    dim3 tb(512);
    dim3 grid(8192 / 128, 1024 / 256);   // 64 x 4 = 256 blocks = 1/CU
    const int WS = 1024 * 256;
    const int US = 1024 * 1024;

    // layer 0 (no recurrence) -> z_a
    icnn_layer_kernel<false, false><<<grid, tb, 0, stream>>>(
        xc_bf, xf_bf, nullptr, Wc_bf, Wu_bf, Wut_bf, nullptr,
        Wc_b, Wu_b, Wut_b, (__hip_bfloat16*)z_a, nullptr);
    // layer 1 -> z_b (in d_out)
    icnn_layer_kernel<true, false><<<grid, tb, 0, stream>>>(
        xc_bf, xf_bf, z_a, Wc_bf + WS, Wu_bf + WS, Wut_bf + WS, U_bf,
        Wc_b + 1024, Wu_b + 1024, Wut_b + 1024, (__hip_bfloat16*)z_b, nullptr);
    // layer 2 -> z_a
    icnn_layer_kernel<true, false><<<grid, tb, 0, stream>>>(
        xc_bf, xf_bf, z_b, Wc_bf + 2 * WS, Wu_bf + 2 * WS, Wut_bf + 2 * WS, U_bf + US,
        Wc_b + 2048, Wu_b + 2048, Wut_b + 2048, (__hip_bfloat16*)z_a, nullptr);
    // layer 3 -> fp32 d_out
    icnn_layer_kernel<true, true><<<grid, tb, 0, stream>>>(
        xc_bf, xf_bf, z_a, Wc_bf + 3 * WS, Wu_bf + 3 * WS, Wut_bf + 3 * WS, U_bf + 2 * US,
        Wc_b + 3072, Wu_b + 3072, Wut_b + 3072, nullptr, (float*)d_out);
}

// Round 7
// 173.192 us; speedup vs baseline: 1.5068x; 1.1643x over previous
//
#include <hip/hip_runtime.h>
#include <hip/hip_bf16.h>
#include <stdint.h>

typedef __attribute__((ext_vector_type(8))) short short8;   // 8 bf16 (4 VGPRs) MFMA A/B frag
typedef __attribute__((ext_vector_type(4))) float f32x4;    // MFMA C/D frag

__device__ __forceinline__ float softplus_f(float x) {
    return (x > 0.f) ? (x + log1pf(expf(-x))) : log1pf(expf(x));
}

// mode 0: plain cast; mode 1: column-monotone (cols 0..3 -> +softplus, 4..7 -> -softplus, rest raw, 256 cols);
// mode 2: softplus everywhere
__global__ void xform_kernel(const float* __restrict__ src, __hip_bfloat16* __restrict__ dst,
                             int n4, int mode) {
    int i = blockIdx.x * blockDim.x + threadIdx.x;
    if (i >= n4) return;
    float4 v = reinterpret_cast<const float4*>(src)[i];
    float r[4] = {v.x, v.y, v.z, v.w};
    int base = i << 2;
#pragma unroll
    for (int j = 0; j < 4; ++j) {
        float x = r[j];
        float y = x;
        if (mode == 2) {
            y = softplus_f(x);
        } else if (mode == 1) {
            int col = (base + j) & 255;
            if (col < 8) {
                float s = softplus_f(x);
                y = (col < 4) ? s : -s;
            }
        }
        dst[base + j] = __float2bfloat16(y);
    }
}

#define GLOAD16(src, dst)                                                                  \
    __builtin_amdgcn_global_load_lds((const __attribute__((address_space(1))) void*)(src), \
                                     (__attribute__((address_space(3))) void*)(dst), 16, 0, 0)

// Fused ICNN layer, round-7 structure:
//  - tile 128x128, 4 waves (2x2), per-wave 64x64 (acc[4][4], 32 MFMA/step)
//  - BK=64, 2 LDS buffers (64KB total) -> TWO blocks/CU (cross-block overlap fills
//    every serial gap; proven R2-vs-R4: 2 blocks/CU matched intra-block pipelining)
//  - ONE __syncthreads per step; order: read frags(s) -> issue stage(s+1) -> MFMA(s).
//    The DMA is in flight across the barrier with a full MFMA cluster to land, so the
//    barrier's vmcnt(0) drain is nearly free (R3/R4 lesson).
//  - bf16 epilogue bounces through LDS (reusing staging buffers) for full-line writes.
// Step map (HAS_U): 0-3 xf@Wut^T (relu'd at step 3), 4-7 xc@Wc^T, 8-11 xf@Wu^T, 12-27 z@U^T.
template<bool HAS_U, bool WRITE_F32>
__global__ __launch_bounds__(256, 2)
void icnn_layer_kernel(const short* __restrict__ xc, const short* __restrict__ xf,
                       const short* __restrict__ zin,
                       const short* __restrict__ Wc, const short* __restrict__ Wu,
                       const short* __restrict__ Wut, const short* __restrict__ U,
                       const float* __restrict__ bc, const float* __restrict__ bu,
                       const float* __restrict__ but,
                       __hip_bfloat16* __restrict__ zout, float* __restrict__ fout)
{
    __shared__ short lds_s[4][128 * 64];   // [0..1]=A bufs, [2..3]=B bufs; 64KB total
    const int t = threadIdx.x;             // 0..255
    const int lane = t & 63;
    const int wid = t >> 6;                // 0..3
    const int wr = wid >> 1, wc = wid & 1; // 2x2 wave grid, 64x64 per wave
    const int l15 = lane & 15, l4 = lane >> 4;
    const int swz = l15 & 7;               // == row&7 for every fragment row this lane reads
    const int brow = blockIdx.x * 128;
    const int bcol = blockIdx.y * 128;

    constexpr int NSTEP = HAS_U ? 28 : 12;

    f32x4 acc[4][4];
#pragma unroll
    for (int m = 0; m < 4; ++m)
#pragma unroll
        for (int n = 0; n < 4; ++n) acc[m][n] = (f32x4){0.f, 0.f, 0.f, 0.f};

    // hoisted u-path bias
    float bt[4];
#pragma unroll
    for (int n = 0; n < 4; ++n) bt[n] = but[bcol + wc * 64 + n * 16 + l15];

    // resolve operands for step s; ld given as shift (256 -> 8, 1024 -> 10)
    auto seg = [&](int s, const short*& A, int& lsa, const short*& B, int& lsb, int& k0) {
        if (s < 4)       { A = xf;  lsa = 8;  B = Wut; lsb = 8;  k0 = s * 64; }
        else if (s < 8)  { A = xc;  lsa = 8;  B = Wc;  lsb = 8;  k0 = (s - 4) * 64; }
        else if (s < 12) { A = xf;  lsa = 8;  B = Wu;  lsb = 8;  k0 = (s - 8) * 64; }
        else             { A = zin; lsa = 10; B = U;   lsb = 10; k0 = (s - 12) * 64; }
    };

    // stage tile for step s into buffer sel; LDS dest linear, source column-chunk XOR-swizzled.
    // A tile 128x64 = 1024 x 16B chunks / 256 threads = 4 per thread; same for B.
    auto stage = [&](int sel, int s) {
        const short *A, *B; int lsa, lsb, k0;
        seg(s, A, lsa, B, lsb, k0);
        short* Ad = &lds_s[sel][0];
        short* Bd = &lds_s[2 + sel][0];
#pragma unroll
        for (int it = 0; it < 4; ++it) {
            int c = it * 256 + t;             // chunk 0..1023; 8 chunks per 64-elem row
            int row = c >> 3;
            int js = (c & 7) ^ (row & 7);     // inverse swizzle on source
            GLOAD16(A + (((size_t)(brow + row)) << lsa) + k0 + js * 8, Ad + c * 8);
        }
#pragma unroll
        for (int it = 0; it < 4; ++it) {
            int c = it * 256 + t;
            int row = c >> 3;
            int js = (c & 7) ^ (row & 7);
            GLOAD16(B + (((size_t)(bcol + row)) << lsb) + k0 + js * 8, Bd + c * 8);
        }
    };

    // ---- prologue ----
    stage(0, 0);

    // ---- main loop: one __syncthreads per step ----
    for (int s = 0; s < NSTEP; ++s) {
        __syncthreads();   // vmcnt(0)+lgkmcnt(0)+barrier: stage(s) landed for all waves;
                           // also: all waves done reading buf[(s+1)&1] (their MFMAs consumed it)

        const int sel = s & 1;
        const short* Asel = &lds_s[sel][0];
        const short* Bsel = &lds_s[2 + sel][0];

        // read ALL 16 fragments for this step (static indexing)
        short8 a[2][4], b[2][4];
#pragma unroll
        for (int kk = 0; kk < 2; ++kk) {
            const int joff = ((kk * 4 + l4) ^ swz) << 3;   // swizzled column offset (shorts)
#pragma unroll
            for (int m = 0; m < 4; ++m)
                a[kk][m] = *(const short8*)&Asel[((wr * 64 + m * 16 + l15) << 6) + joff];
#pragma unroll
            for (int n = 0; n < 4; ++n)
                b[kk][n] = *(const short8*)&Bsel[((wc * 64 + n * 16 + l15) << 6) + joff];
        }

        // issue next tile's DMA; it flies across the next barrier under this step's MFMAs
        if (s + 1 < NSTEP) stage((s + 1) & 1, s + 1);
        __builtin_amdgcn_sched_barrier(0);   // pin reads+DMA issue before the MFMA cluster

        __builtin_amdgcn_s_setprio(1);
#pragma unroll
        for (int kk = 0; kk < 2; ++kk)
#pragma unroll
            for (int m = 0; m < 4; ++m)
#pragma unroll
                for (int n = 0; n < 4; ++n)
                    acc[m][n] = __builtin_amdgcn_mfma_f32_16x16x32_bf16(a[kk][m], b[kk][n], acc[m][n], 0, 0, 0);
        __builtin_amdgcn_s_setprio(0);

        if (s == 3) {
            // u = relu(xf@Wut^T + but); MFMA accumulates the remaining paths on top
#pragma unroll
            for (int n = 0; n < 4; ++n)
#pragma unroll
                for (int m = 0; m < 4; ++m)
#pragma unroll
                    for (int v = 0; v < 4; ++v)
                        acc[m][n][v] = fmaxf(acc[m][n][v] + bt[n], 0.f);
        }
    }

    // ---- epilogue: + (bc + bu), relu ----
    float bb[4];
#pragma unroll
    for (int n = 0; n < 4; ++n) {
        int col = bcol + wc * 64 + n * 16 + l15;
        bb[n] = bc[col] + bu[col];
    }

    if constexpr (WRITE_F32) {
        // f32 path: 16-lane group writes one full 64B line -> direct store
#pragma unroll
        for (int n = 0; n < 4; ++n) {
            int col = bcol + wc * 64 + n * 16 + l15;
#pragma unroll
            for (int m = 0; m < 4; ++m) {
                int row = brow + wr * 64 + m * 16 + l4 * 4;
#pragma unroll
                for (int v = 0; v < 4; ++v)
                    fout[(size_t)(row + v) * 1024 + col] = fmaxf(acc[m][n][v] + bb[n], 0.f);
            }
        }
    } else {
        // bf16 path: bounce through LDS (reuse staging buffers: 64KB = 128x128 f32)
        // to get full-line 64B global writes (direct 2B scatter was 2.5x write-amplified).
        __syncthreads();   // staging buffers dead: all DMA drained, all frag reads consumed
        float* fs = (float*)&lds_s[0][0];
#pragma unroll
        for (int n = 0; n < 4; ++n) {
            int col = wc * 64 + n * 16 + l15;
#pragma unroll
            for (int m = 0; m < 4; ++m) {
                int row = wr * 64 + m * 16 + l4 * 4;
#pragma unroll
                for (int v = 0; v < 4; ++v)
                    fs[(row + v) * 128 + col] = fmaxf(acc[m][n][v] + bb[n], 0.f);
            }
        }
        __syncthreads();
        // 256 threads x 4 f32 per pass = 1024 f32; 16 passes cover 128x128
        const int rrow = t >> 5;           // 0..7
        const int rcol = (t & 31) * 4;     // 0..124
#pragma unroll
        for (int p = 0; p < 16; ++p) {
            int row = p * 8 + rrow;
            float4 v4 = *(const float4*)&fs[row * 128 + rcol];
            ushort4 o;
            o.x = __bfloat16_as_ushort(__float2bfloat16(v4.x));
            o.y = __bfloat16_as_ushort(__float2bfloat16(v4.y));
            o.z = __bfloat16_as_ushort(__float2bfloat16(v4.z));
            o.w = __bfloat16_as_ushort(__float2bfloat16(v4.w));
            *(ushort4*)&zout[(size_t)(brow + row) * 1024 + bcol + rcol] = o;
        }
    }
}

extern "C" void kernel_launch(void* const* d_in, const int* in_sizes, int n_in,
                              void* d_out, int out_size, void* d_ws, size_t ws_size,
                              hipStream_t stream)
{
    const float* xc    = (const float*)d_in[0];
    const float* xf    = (const float*)d_in[1];
    const float* Wc_w  = (const float*)d_in[2];
    const float* Wc_b  = (const float*)d_in[3];
    const float* Wu_w  = (const float*)d_in[4];
    const float* Wu_b  = (const float*)d_in[5];
    const float* Wut_w = (const float*)d_in[6];
    const float* Wut_b = (const float*)d_in[7];
    const float* raw_U = (const float*)d_in[8];

    // workspace layout (bf16 buffers), ~36 MB total
    short* p = (short*)d_ws;
    short* xc_bf  = p; p += 8192 * 256;
    short* xf_bf  = p; p += 8192 * 256;
    short* Wc_bf  = p; p += 4 * 1024 * 256;
    short* Wu_bf  = p; p += 4 * 1024 * 256;
    short* Wut_bf = p; p += 4 * 1024 * 256;
    short* U_bf   = p; p += 3 * 1024 * 1024;
    short* z_a    = p; p += 8192 * 1024;
    // z_b lives in d_out (bf16 scratch); layer 3 fully overwrites d_out with fp32 result.
    short* z_b = (short*)d_out;

    dim3 tb256(256);
    xform_kernel<<<dim3(2048), tb256, 0, stream>>>(xc,    (__hip_bfloat16*)xc_bf,  8192 * 256 / 4, 0);
    xform_kernel<<<dim3(2048), tb256, 0, stream>>>(xf,    (__hip_bfloat16*)xf_bf,  8192 * 256 / 4, 0);
    xform_kernel<<<dim3(1024), tb256, 0, stream>>>(Wc_w,  (__hip_bfloat16*)Wc_bf,  4 * 1024 * 256 / 4, 1);
    xform_kernel<<<dim3(1024), tb256, 0, stream>>>(Wu_w,  (__hip_bfloat16*)Wu_bf,  4 * 1024 * 256 / 4, 1);
    xform_kernel<<<dim3(1024), tb256, 0, stream>>>(Wut_w, (__hip_bfloat16*)Wut_bf, 4 * 1024 * 256 / 4, 1);
    xform_kernel<<<dim3(3072), tb256, 0, stream>>>(raw_U, (__hip_bfloat16*)U_bf,   3 * 1024 * 1024 / 4, 2);

    dim3 tb(256);
    dim3 grid(8192 / 128, 1024 / 128);   // 64 x 8 = 512 blocks = 2/CU
    const int WS = 1024 * 256;
    const int US = 1024 * 1024;

    // layer 0 (no recurrence) -> z_a
    icnn_layer_kernel<false, false><<<grid, tb, 0, stream>>>(
        xc_bf, xf_bf, nullptr, Wc_bf, Wu_bf, Wut_bf, nullptr,
        Wc_b, Wu_b, Wut_b, (__hip_bfloat16*)z_a, nullptr);
    // layer 1 -> z_b (in d_out)
    icnn_layer_kernel<true, false><<<grid, tb, 0, stream>>>(
        xc_bf, xf_bf, z_a, Wc_bf + WS, Wu_bf + WS, Wut_bf + WS, U_bf,
        Wc_b + 1024, Wu_b + 1024, Wut_b + 1024, (__hip_bfloat16*)z_b, nullptr);
    // layer 2 -> z_a
    icnn_layer_kernel<true, false><<<grid, tb, 0, stream>>>(
        xc_bf, xf_bf, z_b, Wc_bf + 2 * WS, Wu_bf + 2 * WS, Wut_bf + 2 * WS, U_bf + US,
        Wc_b + 2048, Wu_b + 2048, Wut_b + 2048, (__hip_bfloat16*)z_a, nullptr);
    // layer 3 -> fp32 d_out
    icnn_layer_kernel<true, true><<<grid, tb, 0, stream>>>(
        xc_bf, xf_bf, z_a, Wc_bf + 3 * WS, Wu_bf + 3 * WS, Wut_bf + 3 * WS, U_bf + 2 * US,
        Wc_b + 3072, Wu_b + 3072, Wut_b + 3072, nullptr, (float*)d_out);
}

// Round 8
// 160.789 us; speedup vs baseline: 1.6230x; 1.0771x over previous
//
#include <hip/hip_runtime.h>
#include <hip/hip_bf16.h>
#include <stdint.h>

typedef __attribute__((ext_vector_type(8))) short short8;   // 8 bf16 (4 VGPRs) MFMA A/B frag
typedef __attribute__((ext_vector_type(4))) float f32x4;    // MFMA C/D frag

__device__ __forceinline__ float softplus_f(float x) {
    return (x > 0.f) ? (x + log1pf(expf(-x))) : log1pf(expf(x));
}

// All six input transforms fused into one launch.
// Regions (float4 units): xc 524288 | xf 524288 | Wc 262144 | Wu 262144 | Wut 262144 | U 786432
__global__ void xform_all(const float* __restrict__ xc, const float* __restrict__ xf,
                          const float* __restrict__ Wc_w, const float* __restrict__ Wu_w,
                          const float* __restrict__ Wut_w, const float* __restrict__ raw_U,
                          short* __restrict__ xc_bf, short* __restrict__ xf_bf,
                          short* __restrict__ Wc_bf, short* __restrict__ Wu_bf,
                          short* __restrict__ Wut_bf, short* __restrict__ U_bf)
{
    int j = blockIdx.x * blockDim.x + threadIdx.x;
    const float* src; short* dst; int mode;
    if (j < 524288)                    { src = xc;    dst = xc_bf;  mode = 0; }
    else if ((j -= 524288) < 524288)   { src = xf;    dst = xf_bf;  mode = 0; }
    else if ((j -= 524288) < 262144)   { src = Wc_w;  dst = Wc_bf;  mode = 1; }
    else if ((j -= 262144) < 262144)   { src = Wu_w;  dst = Wu_bf;  mode = 1; }
    else if ((j -= 262144) < 262144)   { src = Wut_w; dst = Wut_bf; mode = 1; }
    else                               { j -= 262144; src = raw_U;  dst = U_bf;  mode = 2; }
    float4 v = reinterpret_cast<const float4*>(src)[j];
    float r[4] = {v.x, v.y, v.z, v.w};
    int base = j << 2;
#pragma unroll
    for (int e = 0; e < 4; ++e) {
        float x = r[e];
        float y = x;
        if (mode == 2) {
            y = softplus_f(x);
        } else if (mode == 1) {
            int col = (base + e) & 255;
            if (col < 8) {
                float s = softplus_f(x);
                y = (col < 4) ? s : -s;
            }
        }
        ((__hip_bfloat16*)dst)[base + e] = __float2bfloat16(y);
    }
}

#define GLOAD16(src, dst)                                                                  \
    __builtin_amdgcn_global_load_lds((const __attribute__((address_space(1))) void*)(src), \
                                     (__attribute__((address_space(3))) void*)(dst), 16, 0, 0)

// Fused ICNN layer — round-8 (T3+T4 faithful port):
//  - BM=256 x BN=128, grid 32x8 = 256 blocks = 1/CU; 8 waves (4M x 2N), per-wave 64x64
//  - BK=64; THREE statically-named LDS buffer pairs (separate __shared__ arrays so the
//    compiler's alias analysis proves ds_read(bufX) independent of in-flight DMA(bufY) —
//    kills the conservative vmcnt(0) drains that nullified R3-R6's pipelines)
//  - per K-tile: vmcnt(6)+s_barrier at top (counted, never 0 until the last tile), then
//    2 phases of {8 ds_read | 3 DMA of stage(t+2) | s_barrier | lgkmcnt(0)+sched_barrier |
//    setprio(1) 16 MFMA setprio(0)}; MFMA retirement drains under next phase's reads.
//  - stage(t+2) targets buf((t+2)%3) = buffer last read at tile t-1; tile-t top barrier
//    proves those reads complete -> no write-after-read race.
// Step map (HAS_U): 0-3 xf@Wut^T (relu'd at t=3), 4-7 xc@Wc^T, 8-11 xf@Wu^T, 12-27 z@U^T.
template<bool HAS_U, bool WRITE_F32>
__global__ __launch_bounds__(512, 2)
void icnn_layer_kernel(const short* __restrict__ xc, const short* __restrict__ xf,
                       const short* __restrict__ zin,
                       const short* __restrict__ Wc, const short* __restrict__ Wu,
                       const short* __restrict__ Wut, const short* __restrict__ U,
                       const float* __restrict__ bc, const float* __restrict__ bu,
                       const float* __restrict__ but,
                       __hip_bfloat16* __restrict__ zout, float* __restrict__ fout)
{
    __shared__ short A0s[256 * 64], A1s[256 * 64], A2s[256 * 64];   // 32KB each
    __shared__ short B0s[128 * 64], B1s[128 * 64], B2s[128 * 64];   // 16KB each; total 144KB
    const int t_ = threadIdx.x;            // 0..511
    const int lane = t_ & 63;
    const int wid = t_ >> 6;               // 0..7
    const int wr = wid >> 1, wc = wid & 1; // 4M x 2N wave grid; 64x64 per wave
    const int l15 = lane & 15, l4 = lane >> 4;
    const int swz = l15 & 7;               // == row&7 for every fragment row this lane reads
    const int brow = blockIdx.x * 256;
    const int bcol = blockIdx.y * 128;

    constexpr int NSTEP = HAS_U ? 28 : 12;

    f32x4 acc[4][4];
#pragma unroll
    for (int m = 0; m < 4; ++m)
#pragma unroll
        for (int n = 0; n < 4; ++n) acc[m][n] = (f32x4){0.f, 0.f, 0.f, 0.f};

    float bt[4];
#pragma unroll
    for (int n = 0; n < 4; ++n) bt[n] = but[bcol + wc * 64 + n * 16 + l15];

    // resolve operands for step s; ld as shift (256 -> 8, 1024 -> 10)
    auto seg = [&](int s, const short*& A, int& lsa, const short*& B, int& lsb, int& k0) {
        if (s < 4)       { A = xf;  lsa = 8;  B = Wut; lsb = 8;  k0 = s * 64; }
        else if (s < 8)  { A = xc;  lsa = 8;  B = Wc;  lsb = 8;  k0 = (s - 4) * 64; }
        else if (s < 12) { A = xf;  lsa = 8;  B = Wu;  lsb = 8;  k0 = (s - 8) * 64; }
        else             { A = zin; lsa = 10; B = U;   lsb = 10; k0 = (s - 12) * 64; }
    };

    // half-stage: part 0 = A chunks it=0,1 + B chunk it=0; part 1 = A it=2,3 + B it=1.
    // A tile 256x64 = 2048 16B-chunks (4/thread); B tile 128x64 = 1024 (2/thread).
    auto stage_half = [&](short* Ad, short* Bd, const short* Ag, int lsa,
                          const short* Bg, int lsb, int k0, int part) {
#pragma unroll
        for (int it = 0; it < 2; ++it) {
            int c = (part * 2 + it) * 512 + t_;
            int row = c >> 3;                 // 8 chunks per 64-elem row
            int js = (c & 7) ^ (row & 7);     // inverse swizzle on source
            GLOAD16(Ag + (((size_t)(brow + row)) << lsa) + k0 + js * 8, Ad + c * 8);
        }
        {
            int c = part * 512 + t_;
            int row = c >> 3;
            int js = (c & 7) ^ (row & 7);
            GLOAD16(Bg + (((size_t)(bcol + row)) << lsb) + k0 + js * 8, Bd + c * 8);
        }
    };

    // one K-tile: read As/Bs (tile t), stage t+2 into As2/Bs2 (all statically named)
    auto tile = [&](short* As, short* Bs, short* As2, short* Bs2, int t) {
        if (t + 1 < NSTEP) asm volatile("s_waitcnt vmcnt(6)" ::: "memory");
        else               asm volatile("s_waitcnt vmcnt(0)" ::: "memory");
        __builtin_amdgcn_s_barrier();

        const short *Ag = nullptr, *Bg = nullptr; int lsa = 8, lsb = 8, k0 = 0;
        const bool doStage = (t + 2 < NSTEP);
        if (doStage) seg(t + 2, Ag, lsa, Bg, lsb, k0);

#pragma unroll
        for (int kk = 0; kk < 2; ++kk) {
            short8 a[4], b[4];
            const int joff = ((kk * 4 + l4) ^ swz) << 3;   // swizzled column offset (shorts)
#pragma unroll
            for (int m = 0; m < 4; ++m)
                a[m] = *(const short8*)&As[((wr * 64 + m * 16 + l15) << 6) + joff];
#pragma unroll
            for (int n = 0; n < 4; ++n)
                b[n] = *(const short8*)&Bs[((wc * 64 + n * 16 + l15) << 6) + joff];

            if (doStage) stage_half(As2, Bs2, Ag, lsa, Bg, lsb, k0, kk);

            __builtin_amdgcn_sched_barrier(0);               // pin reads+DMA above barrier
            __builtin_amdgcn_s_barrier();                    // all waves issued this phase
            asm volatile("s_waitcnt lgkmcnt(0)" ::: "memory");  // my frags landed
            __builtin_amdgcn_sched_barrier(0);               // rule 18: keep MFMA below wait

            __builtin_amdgcn_s_setprio(1);
#pragma unroll
            for (int m = 0; m < 4; ++m)
#pragma unroll
                for (int n = 0; n < 4; ++n)
                    acc[m][n] = __builtin_amdgcn_mfma_f32_16x16x32_bf16(a[m], b[n], acc[m][n], 0, 0, 0);
            __builtin_amdgcn_s_setprio(0);
        }

        if (t == 3) {
            // u = relu(xf@Wut^T + but); MFMA accumulates the remaining paths on top
#pragma unroll
            for (int n = 0; n < 4; ++n)
#pragma unroll
                for (int m = 0; m < 4; ++m)
#pragma unroll
                    for (int v = 0; v < 4; ++v)
                        acc[m][n][v] = fmaxf(acc[m][n][v] + bt[n], 0.f);
        }
    };

    // ---- prologue: 2 tiles in flight ----
    {
        const short *Ag, *Bg; int lsa, lsb, k0;
        seg(0, Ag, lsa, Bg, lsb, k0);
        stage_half(A0s, B0s, Ag, lsa, Bg, lsb, k0, 0);
        stage_half(A0s, B0s, Ag, lsa, Bg, lsb, k0, 1);
        seg(1, Ag, lsa, Bg, lsb, k0);
        stage_half(A1s, B1s, Ag, lsa, Bg, lsb, k0, 0);
        stage_half(A1s, B1s, Ag, lsa, Bg, lsb, k0, 1);
    }

    // ---- main loop: triples keep buffer identity compile-time ----
    int t = 0;
    for (int i = 0; i < NSTEP / 3; ++i) {
        tile(A0s, B0s, A2s, B2s, t);
        tile(A1s, B1s, A0s, B0s, t + 1);
        tile(A2s, B2s, A1s, B1s, t + 2);
        t += 3;
    }
    if (NSTEP % 3) tile(A0s, B0s, A2s, B2s, t);   // NSTEP=28: leftover t=27 reads buf0

    // ---- epilogue: + (bc + bu), relu, store ----
    float bb[4];
#pragma unroll
    for (int n = 0; n < 4; ++n) {
        int col = bcol + wc * 64 + n * 16 + l15;
        bb[n] = bc[col] + bu[col];
    }

    if constexpr (WRITE_F32) {
        // f32: 16-lane group writes one full 64B line per (m,n,v) -> direct store
#pragma unroll
        for (int n = 0; n < 4; ++n) {
            int col = bcol + wc * 64 + n * 16 + l15;
#pragma unroll
            for (int m = 0; m < 4; ++m) {
                int row = brow + wr * 64 + m * 16 + l4 * 4;
#pragma unroll
                for (int v = 0; v < 4; ++v)
                    fout[(size_t)(row + v) * 1024 + col] = fmaxf(acc[m][n][v] + bb[n], 0.f);
            }
        }
    } else {
        // bf16: bounce via LDS (A0s as [64][128] f32, 32KB) in 4 chunks (one per wr)
        float* fs = (float*)A0s;
#pragma unroll
        for (int c = 0; c < 4; ++c) {
            __syncthreads();
            if (wr == c) {
#pragma unroll
                for (int n = 0; n < 4; ++n) {
                    int col = wc * 64 + n * 16 + l15;
#pragma unroll
                    for (int m = 0; m < 4; ++m) {
                        int row = m * 16 + l4 * 4;
#pragma unroll
                        for (int v = 0; v < 4; ++v)
                            fs[(row + v) * 128 + col] = fmaxf(acc[m][n][v] + bb[n], 0.f);
                    }
                }
            }
            __syncthreads();
            // 512 threads x 4 f32 x 4 passes = 8192 f32 = 64x128
#pragma unroll
            for (int p = 0; p < 4; ++p) {
                int row = p * 16 + (t_ >> 5);
                int col = (t_ & 31) * 4;
                float4 v4 = *(const float4*)&fs[row * 128 + col];
                ushort4 o;
                o.x = __bfloat16_as_ushort(__float2bfloat16(v4.x));
                o.y = __bfloat16_as_ushort(__float2bfloat16(v4.y));
                o.z = __bfloat16_as_ushort(__float2bfloat16(v4.z));
                o.w = __bfloat16_as_ushort(__float2bfloat16(v4.w));
                *(ushort4*)&zout[(size_t)(brow + c * 64 + row) * 1024 + bcol + col] = o;
            }
        }
    }
}

extern "C" void kernel_launch(void* const* d_in, const int* in_sizes, int n_in,
                              void* d_out, int out_size, void* d_ws, size_t ws_size,
                              hipStream_t stream)
{
    const float* xc    = (const float*)d_in[0];
    const float* xf    = (const float*)d_in[1];
    const float* Wc_w  = (const float*)d_in[2];
    const float* Wc_b  = (const float*)d_in[3];
    const float* Wu_w  = (const float*)d_in[4];
    const float* Wu_b  = (const float*)d_in[5];
    const float* Wut_w = (const float*)d_in[6];
    const float* Wut_b = (const float*)d_in[7];
    const float* raw_U = (const float*)d_in[8];

    // workspace layout (bf16 buffers), ~36 MB total
    short* p = (short*)d_ws;
    short* xc_bf  = p; p += 8192 * 256;
    short* xf_bf  = p; p += 8192 * 256;
    short* Wc_bf  = p; p += 4 * 1024 * 256;
    short* Wu_bf  = p; p += 4 * 1024 * 256;
    short* Wut_bf = p; p += 4 * 1024 * 256;
    short* U_bf   = p; p += 3 * 1024 * 1024;
    short* z_a    = p; p += 8192 * 1024;
    // z_b lives in d_out (bf16 scratch); layer 3 fully overwrites d_out with fp32 result.
    short* z_b = (short*)d_out;

    xform_all<<<dim3(10240), dim3(256), 0, stream>>>(
        xc, xf, Wc_w, Wu_w, Wut_w, raw_U,
        xc_bf, xf_bf, Wc_bf, Wu_bf, Wut_bf, U_bf);

    dim3 tb(512);
    dim3 grid(8192 / 256, 1024 / 128);   // 32 x 8 = 256 blocks = 1/CU
    const int WS = 1024 * 256;
    const int US = 1024 * 1024;

    // layer 0 (no recurrence) -> z_a
    icnn_layer_kernel<false, false><<<grid, tb, 0, stream>>>(
        xc_bf, xf_bf, nullptr, Wc_bf, Wu_bf, Wut_bf, nullptr,
        Wc_b, Wu_b, Wut_b, (__hip_bfloat16*)z_a, nullptr);
    // layer 1 -> z_b (in d_out)
    icnn_layer_kernel<true, false><<<grid, tb, 0, stream>>>(
        xc_bf, xf_bf, z_a, Wc_bf + WS, Wu_bf + WS, Wut_bf + WS, U_bf,
        Wc_b + 1024, Wu_b + 1024, Wut_b + 1024, (__hip_bfloat16*)z_b, nullptr);
    // layer 2 -> z_a
    icnn_layer_kernel<true, false><<<grid, tb, 0, stream>>>(
        xc_bf, xf_bf, z_b, Wc_bf + 2 * WS, Wu_bf + 2 * WS, Wut_bf + 2 * WS, U_bf + US,
        Wc_b + 2048, Wu_b + 2048, Wut_b + 2048, (__hip_bfloat16*)z_a, nullptr);
    // layer 3 -> fp32 d_out
    icnn_layer_kernel<true, true><<<grid, tb, 0, stream>>>(
        xc_bf, xf_bf, z_a, Wc_bf + 3 * WS, Wu_bf + 3 * WS, Wut_bf + 3 * WS, U_bf + 2 * US,
        Wc_b + 3072, Wu_b + 3072, Wut_b + 3072, nullptr, (float*)d_out);
}

// Round 9
// 155.467 us; speedup vs baseline: 1.6786x; 1.0342x over previous
//
#include <hip/hip_runtime.h>
#include <hip/hip_bf16.h>
#include <stdint.h>

typedef __attribute__((ext_vector_type(8))) short short8;   // 8 bf16 (4 VGPRs) MFMA A/B frag
typedef __attribute__((ext_vector_type(4))) float f32x4;    // MFMA C/D frag

__device__ __forceinline__ float softplus_f(float x) {
    return (x > 0.f) ? (x + log1pf(expf(-x))) : log1pf(expf(x));
}

// All six input transforms fused into one launch.
// Regions (float4 units): xc 524288 | xf 524288 | Wc 262144 | Wu 262144 | Wut 262144 | U 786432
__global__ void xform_all(const float* __restrict__ xc, const float* __restrict__ xf,
                          const float* __restrict__ Wc_w, const float* __restrict__ Wu_w,
                          const float* __restrict__ Wut_w, const float* __restrict__ raw_U,
                          short* __restrict__ xc_bf, short* __restrict__ xf_bf,
                          short* __restrict__ Wc_bf, short* __restrict__ Wu_bf,
                          short* __restrict__ Wut_bf, short* __restrict__ U_bf)
{
    int j = blockIdx.x * blockDim.x + threadIdx.x;
    const float* src; short* dst; int mode;
    if (j < 524288)                    { src = xc;    dst = xc_bf;  mode = 0; }
    else if ((j -= 524288) < 524288)   { src = xf;    dst = xf_bf;  mode = 0; }
    else if ((j -= 524288) < 262144)   { src = Wc_w;  dst = Wc_bf;  mode = 1; }
    else if ((j -= 262144) < 262144)   { src = Wu_w;  dst = Wu_bf;  mode = 1; }
    else if ((j -= 262144) < 262144)   { src = Wut_w; dst = Wut_bf; mode = 1; }
    else                               { j -= 262144; src = raw_U;  dst = U_bf;  mode = 2; }
    float4 v = reinterpret_cast<const float4*>(src)[j];
    float r[4] = {v.x, v.y, v.z, v.w};
    int base = j << 2;
#pragma unroll
    for (int e = 0; e < 4; ++e) {
        float x = r[e];
        float y = x;
        if (mode == 2) {
            y = softplus_f(x);
        } else if (mode == 1) {
            int col = (base + e) & 255;
            if (col < 8) {
                float s = softplus_f(x);
                y = (col < 4) ? s : -s;
            }
        }
        ((__hip_bfloat16*)dst)[base + e] = __float2bfloat16(y);
    }
}

#define GLOAD16(src, dst)                                                                  \
    __builtin_amdgcn_global_load_lds((const __attribute__((address_space(1))) void*)(src), \
                                     (__attribute__((address_space(3))) void*)(dst), 16, 0, 0)

// inline-asm ds_read_b128: INVISIBLE to the compiler's waitcnt pass, so it cannot insert
// the conservative vmcnt(0)-before-ds_read drain that nullified R2-R8's pipelines.
// Ordering is 100% ours: top-of-tile vmcnt(0)+s_barrier (RAW) and lgkmcnt(0)+sched_barrier
// before MFMA (rule 18).
#define DSREAD(dst, addr, off_lit) \
    asm volatile("ds_read_b128 %0, %1 offset:" #off_lit : "=v"(dst) : "v"(addr))

__device__ __forceinline__ uint32_t lds_addr32(const short* p) {
    // low 32 bits of an LDS generic address == LDS byte offset (AS3 aperture is high bits)
    return (uint32_t)(uintptr_t)(const __attribute__((address_space(3))) short*)p;
}

// Fused ICNN layer — round-9: R7 geometry + asm ds_reads + explicit counted waits.
//  - tile 128x128, 4 waves (2x2), per-wave 64x64 (acc[4][4]); grid 64x8=512 = 2 blocks/CU
//  - BK=64, 2 LDS buffer pairs (64KB/block -> 2 blocks = 128KB/CU)
//  - per tile t: vmcnt(0) [stage(t), issued a FULL tile (~1600cyc) earlier -> near-free]
//    -> raw s_barrier -> 16 asm ds_read_b128 -> issue stage(t+1) -> lgkmcnt(0)
//    -> sched_barrier(0) -> setprio(1) 32 MFMA setprio(0).
//  - WAR safe: stage(t+1) overwrites the buffer whose reads all waves completed before
//    passing this tile's top barrier (their lgkmcnt(0) precedes the barrier in prog order).
// Step map (HAS_U): t 0-3 xf@Wut^T (relu'd at t=3), 4-7 xc@Wc^T, 8-11 xf@Wu^T, 12-27 z@U^T.
template<bool HAS_U, bool WRITE_F32>
__global__ __launch_bounds__(256, 2)
void icnn_layer_kernel(const short* __restrict__ xc, const short* __restrict__ xf,
                       const short* __restrict__ zin,
                       const short* __restrict__ Wc, const short* __restrict__ Wu,
                       const short* __restrict__ Wut, const short* __restrict__ U,
                       const float* __restrict__ bc, const float* __restrict__ bu,
                       const float* __restrict__ but,
                       __hip_bfloat16* __restrict__ zout, float* __restrict__ fout)
{
    __shared__ short lds_s[4][128 * 64];   // [0],[1]=A bufs; [2],[3]=B bufs; 64KB
    const int t_ = threadIdx.x;            // 0..255
    const int lane = t_ & 63;
    const int wid = t_ >> 6;               // 0..3
    const int wr = wid >> 1, wc = wid & 1; // 2x2 wave grid; 64x64 per wave
    const int l15 = lane & 15, l4 = lane >> 4;
    const int swz = l15 & 7;               // == row&7 for every fragment row this lane reads
    const int brow = blockIdx.x * 128;
    const int bcol = blockIdx.y * 128;

    constexpr int NSTEP = HAS_U ? 28 : 12;

    f32x4 acc[4][4];
#pragma unroll
    for (int m = 0; m < 4; ++m)
#pragma unroll
        for (int n = 0; n < 4; ++n) acc[m][n] = (f32x4){0.f, 0.f, 0.f, 0.f};

    float bt[4];
#pragma unroll
    for (int n = 0; n < 4; ++n) bt[n] = but[bcol + wc * 64 + n * 16 + l15];

    // resolve operands for step s; ld as shift (256 -> 8, 1024 -> 10)
    auto seg = [&](int s, const short*& A, int& lsa, const short*& B, int& lsb, int& k0) {
        if (s < 4)       { A = xf;  lsa = 8;  B = Wut; lsb = 8;  k0 = s * 64; }
        else if (s < 8)  { A = xc;  lsa = 8;  B = Wc;  lsb = 8;  k0 = (s - 4) * 64; }
        else if (s < 12) { A = xf;  lsa = 8;  B = Wu;  lsb = 8;  k0 = (s - 8) * 64; }
        else             { A = zin; lsa = 10; B = U;   lsb = 10; k0 = (s - 12) * 64; }
    };

    // stage tile for step s; LDS dest linear, source column-chunk XOR-swizzled.
    // A 128x64 = 1024 16B-chunks / 256 thr = 4 each; B same. 8 loads/thread.
    auto stage = [&](short* Ad, short* Bd, int s) {
        const short *Ag, *Bg; int lsa, lsb, k0;
        seg(s, Ag, lsa, Bg, lsb, k0);
#pragma unroll
        for (int it = 0; it < 4; ++it) {
            int c = it * 256 + t_;
            int row = c >> 3;                 // 8 chunks per 64-elem row
            int js = (c & 7) ^ (row & 7);     // inverse swizzle on source
            GLOAD16(Ag + (((size_t)(brow + row)) << lsa) + k0 + js * 8, Ad + c * 8);
        }
#pragma unroll
        for (int it = 0; it < 4; ++it) {
            int c = it * 256 + t_;
            int row = c >> 3;
            int js = (c & 7) ^ (row & 7);
            GLOAD16(Bg + (((size_t)(bcol + row)) << lsb) + k0 + js * 8, Bd + c * 8);
        }
    };

    auto tile = [&](const short* As, const short* Bs, short* An, short* Bn, int t) {
        // stage(t) was issued one full tile ago -> this wait is nearly free
        asm volatile("s_waitcnt vmcnt(0)" ::: "memory");
        __builtin_amdgcn_s_barrier();

        // fragment base addresses (bytes); row stride 128B, col-chunk XOR-swizzled
        const uint32_t abase = lds_addr32(As) + ((uint32_t)(wr * 64 + l15) << 7);
        const uint32_t bbase = lds_addr32(Bs) + ((uint32_t)(wc * 64 + l15) << 7);
        const uint32_t a0 = abase + (uint32_t)((l4 ^ swz) << 4);
        const uint32_t a1 = abase + (uint32_t)(((4 + l4) ^ swz) << 4);
        const uint32_t b0 = bbase + (uint32_t)((l4 ^ swz) << 4);
        const uint32_t b1 = bbase + (uint32_t)(((4 + l4) ^ swz) << 4);

        short8 a[2][4], b[2][4];
        DSREAD(a[0][0], a0, 0);    DSREAD(a[0][1], a0, 2048);
        DSREAD(a[0][2], a0, 4096); DSREAD(a[0][3], a0, 6144);
        DSREAD(b[0][0], b0, 0);    DSREAD(b[0][1], b0, 2048);
        DSREAD(b[0][2], b0, 4096); DSREAD(b[0][3], b0, 6144);
        DSREAD(a[1][0], a1, 0);    DSREAD(a[1][1], a1, 2048);
        DSREAD(a[1][2], a1, 4096); DSREAD(a[1][3], a1, 6144);
        DSREAD(b[1][0], b1, 0);    DSREAD(b[1][1], b1, 2048);
        DSREAD(b[1][2], b1, 4096); DSREAD(b[1][3], b1, 6144);

        // next tile's DMA: a full tile (~1600cyc) to land before its vmcnt(0)
        if (t + 1 < NSTEP) stage(An, Bn, t + 1);

        asm volatile("s_waitcnt lgkmcnt(0)" ::: "memory");
        __builtin_amdgcn_sched_barrier(0);   // rule 18: MFMA must not hoist above the wait

        __builtin_amdgcn_s_setprio(1);
#pragma unroll
        for (int kk = 0; kk < 2; ++kk)
#pragma unroll
            for (int m = 0; m < 4; ++m)
#pragma unroll
                for (int n = 0; n < 4; ++n)
                    acc[m][n] = __builtin_amdgcn_mfma_f32_16x16x32_bf16(a[kk][m], b[kk][n], acc[m][n], 0, 0, 0);
        __builtin_amdgcn_s_setprio(0);

        if (t == 3) {
            // u = relu(xf@Wut^T + but); MFMA accumulates the remaining paths on top
#pragma unroll
            for (int n = 0; n < 4; ++n)
#pragma unroll
                for (int m = 0; m < 4; ++m)
#pragma unroll
                    for (int v = 0; v < 4; ++v)
                        acc[m][n][v] = fmaxf(acc[m][n][v] + bt[n], 0.f);
        }
    };

    // ---- prologue ----
    stage(lds_s[0], lds_s[2], 0);

    // ---- main loop: buffer identity compile-time via x2 unroll (NSTEP even) ----
    for (int i = 0; i < NSTEP / 2; ++i) {
        tile(lds_s[0], lds_s[2], lds_s[1], lds_s[3], 2 * i);
        tile(lds_s[1], lds_s[3], lds_s[0], lds_s[2], 2 * i + 1);
    }

    // ---- epilogue: + (bc + bu), relu, store ----
    float bb[4];
#pragma unroll
    for (int n = 0; n < 4; ++n) {
        int col = bcol + wc * 64 + n * 16 + l15;
        bb[n] = bc[col] + bu[col];
    }

    if constexpr (WRITE_F32) {
        // f32: 16 consecutive lanes cover one full 64B line -> direct store
#pragma unroll
        for (int n = 0; n < 4; ++n) {
            int col = bcol + wc * 64 + n * 16 + l15;
#pragma unroll
            for (int m = 0; m < 4; ++m) {
                int row = brow + wr * 64 + m * 16 + l4 * 4;
#pragma unroll
                for (int v = 0; v < 4; ++v)
                    fout[(size_t)(row + v) * 1024 + col] = fmaxf(acc[m][n][v] + bb[n], 0.f);
            }
        }
    } else {
        // bf16: bounce via LDS (64KB = 128x128 f32) for full-line 64B global writes
        __syncthreads();   // all DMA drained (last tile waited vmcnt(0)); all frag reads done
        float* fs = (float*)&lds_s[0][0];
#pragma unroll
        for (int n = 0; n < 4; ++n) {
            int col = wc * 64 + n * 16 + l15;
#pragma unroll
            for (int m = 0; m < 4; ++m) {
                int row = wr * 64 + m * 16 + l4 * 4;
#pragma unroll
                for (int v = 0; v < 4; ++v)
                    fs[(row + v) * 128 + col] = fmaxf(acc[m][n][v] + bb[n], 0.f);
            }
        }
        __syncthreads();
        const int rrow = t_ >> 5;          // 0..7
        const int rcol = (t_ & 31) * 4;    // 0..124
#pragma unroll
        for (int p = 0; p < 16; ++p) {
            int row = p * 8 + rrow;
            float4 v4 = *(const float4*)&fs[row * 128 + rcol];
            ushort4 o;
            o.x = __bfloat16_as_ushort(__float2bfloat16(v4.x));
            o.y = __bfloat16_as_ushort(__float2bfloat16(v4.y));
            o.z = __bfloat16_as_ushort(__float2bfloat16(v4.z));
            o.w = __bfloat16_as_ushort(__float2bfloat16(v4.w));
            *(ushort4*)&zout[(size_t)(brow + row) * 1024 + bcol + rcol] = o;
        }
    }
}

extern "C" void kernel_launch(void* const* d_in, const int* in_sizes, int n_in,
                              void* d_out, int out_size, void* d_ws, size_t ws_size,
                              hipStream_t stream)
{
    const float* xc    = (const float*)d_in[0];
    const float* xf    = (const float*)d_in[1];
    const float* Wc_w  = (const float*)d_in[2];
    const float* Wc_b  = (const float*)d_in[3];
    const float* Wu_w  = (const float*)d_in[4];
    const float* Wu_b  = (const float*)d_in[5];
    const float* Wut_w = (const float*)d_in[6];
    const float* Wut_b = (const float*)d_in[7];
    const float* raw_U = (const float*)d_in[8];

    // workspace layout (bf16 buffers), ~36 MB total
    short* p = (short*)d_ws;
    short* xc_bf  = p; p += 8192 * 256;
    short* xf_bf  = p; p += 8192 * 256;
    short* Wc_bf  = p; p += 4 * 1024 * 256;
    short* Wu_bf  = p; p += 4 * 1024 * 256;
    short* Wut_bf = p; p += 4 * 1024 * 256;
    short* U_bf   = p; p += 3 * 1024 * 1024;
    short* z_a    = p; p += 8192 * 1024;
    // z_b lives in d_out (bf16 scratch); layer 3 fully overwrites d_out with fp32 result.
    short* z_b = (short*)d_out;

    xform_all<<<dim3(10240), dim3(256), 0, stream>>>(
        xc, xf, Wc_w, Wu_w, Wut_w, raw_U,
        xc_bf, xf_bf, Wc_bf, Wu_bf, Wut_bf, U_bf);

    dim3 tb(256);
    dim3 grid(8192 / 128, 1024 / 128);   // 64 x 8 = 512 blocks = 2/CU
    const int WS = 1024 * 256;
    const int US = 1024 * 1024;

    // layer 0 (no recurrence) -> z_a
    icnn_layer_kernel<false, false><<<grid, tb, 0, stream>>>(
        xc_bf, xf_bf, nullptr, Wc_bf, Wu_bf, Wut_bf, nullptr,
        Wc_b, Wu_b, Wut_b, (__hip_bfloat16*)z_a, nullptr);
    // layer 1 -> z_b (in d_out)
    icnn_layer_kernel<true, false><<<grid, tb, 0, stream>>>(
        xc_bf, xf_bf, z_a, Wc_bf + WS, Wu_bf + WS, Wut_bf + WS, U_bf,
        Wc_b + 1024, Wu_b + 1024, Wut_b + 1024, (__hip_bfloat16*)z_b, nullptr);
    // layer 2 -> z_a
    icnn_layer_kernel<true, false><<<grid, tb, 0, stream>>>(
        xc_bf, xf_bf, z_b, Wc_bf + 2 * WS, Wu_bf + 2 * WS, Wut_bf + 2 * WS, U_bf + US,
        Wc_b + 2048, Wu_b + 2048, Wut_b + 2048, (__hip_bfloat16*)z_a, nullptr);
    // layer 3 -> fp32 d_out
    icnn_layer_kernel<true, true><<<grid, tb, 0, stream>>>(
        xc_bf, xf_bf, z_a, Wc_bf + 3 * WS, Wu_bf + 3 * WS, Wut_bf + 3 * WS, U_bf + 2 * US,
        Wc_b + 3072, Wu_b + 3072, Wut_b + 3072, nullptr, (float*)d_out);
}

// Round 10
// 125.399 us; speedup vs baseline: 2.0811x; 1.2398x over previous
//
#include <hip/hip_runtime.h>
#include <hip/hip_bf16.h>
#include <stdint.h>

typedef __attribute__((ext_vector_type(8))) short short8;   // 8 bf16 (4 VGPRs) MFMA A/B frag
typedef __attribute__((ext_vector_type(4))) float f32x4;    // MFMA C/D frag

// Fast softplus: max(x,0) + log(1+exp(-|x|)), via v_exp_f32/v_log_f32 HW transcendentals.
// arg of __logf is in (1,2] -> well-conditioned; rel err ~2^-21, invisible at bf16 (2^-8).
__device__ __forceinline__ float softplus_f(float x) {
    float e = __expf(-fabsf(x));
    return fmaxf(x, 0.f) + __logf(1.f + e);
}

// All six input transforms fused into one launch.
// Regions (float4 units): xc 524288 | xf 524288 | Wc 262144 | Wu 262144 | Wut 262144 | U 786432
__global__ void xform_all(const float* __restrict__ xc, const float* __restrict__ xf,
                          const float* __restrict__ Wc_w, const float* __restrict__ Wu_w,
                          const float* __restrict__ Wut_w, const float* __restrict__ raw_U,
                          short* __restrict__ xc_bf, short* __restrict__ xf_bf,
                          short* __restrict__ Wc_bf, short* __restrict__ Wu_bf,
                          short* __restrict__ Wut_bf, short* __restrict__ U_bf)
{
    int j = blockIdx.x * blockDim.x + threadIdx.x;
    const float* src; short* dst; int mode;
    if (j < 524288)                    { src = xc;    dst = xc_bf;  mode = 0; }
    else if ((j -= 524288) < 524288)   { src = xf;    dst = xf_bf;  mode = 0; }
    else if ((j -= 524288) < 262144)   { src = Wc_w;  dst = Wc_bf;  mode = 1; }
    else if ((j -= 262144) < 262144)   { src = Wu_w;  dst = Wu_bf;  mode = 1; }
    else if ((j -= 262144) < 262144)   { src = Wut_w; dst = Wut_bf; mode = 1; }
    else                               { j -= 262144; src = raw_U;  dst = U_bf;  mode = 2; }
    float4 v = reinterpret_cast<const float4*>(src)[j];
    float r[4] = {v.x, v.y, v.z, v.w};
    int base = j << 2;
#pragma unroll
    for (int e = 0; e < 4; ++e) {
        float x = r[e];
        float y = x;
        if (mode == 2) {
            y = softplus_f(x);
        } else if (mode == 1) {
            int col = (base + e) & 255;
            if (col < 8) {
                float s = softplus_f(x);
                y = (col < 4) ? s : -s;
            }
        }
        ((__hip_bfloat16*)dst)[base + e] = __float2bfloat16(y);
    }
}

#define GLOAD16(src, dst)                                                                  \
    __builtin_amdgcn_global_load_lds((const __attribute__((address_space(1))) void*)(src), \
                                     (__attribute__((address_space(3))) void*)(dst), 16, 0, 0)

// inline-asm ds_read_b128: INVISIBLE to the compiler's waitcnt pass, so it cannot insert
// the conservative vmcnt(0)-before-ds_read drain that nullified R2-R8's pipelines.
// Ordering is 100% ours: top-of-tile vmcnt(0)+s_barrier (RAW) and lgkmcnt(0)+sched_barrier
// before MFMA (rule 18).
#define DSREAD(dst, addr, off_lit) \
    asm volatile("ds_read_b128 %0, %1 offset:" #off_lit : "=v"(dst) : "v"(addr))

__device__ __forceinline__ uint32_t lds_addr32(const short* p) {
    // low 32 bits of an LDS generic address == LDS byte offset (AS3 aperture is high bits)
    return (uint32_t)(uintptr_t)(const __attribute__((address_space(3))) short*)p;
}

// Fused ICNN layer — round-9 structure (proven): asm ds_reads + explicit counted waits.
//  - tile 128x128, 4 waves (2x2), per-wave 64x64 (acc[4][4]); grid 64x8=512 = 2 blocks/CU
//  - BK=64, 2 LDS buffer pairs (64KB/block -> 2 blocks = 128KB/CU)
//  - per tile t: vmcnt(0) [stage(t), issued a FULL tile (~1400cyc) earlier -> near-free]
//    -> raw s_barrier -> 16 asm ds_read_b128 -> issue stage(t+1) -> lgkmcnt(0)
//    -> sched_barrier(0) -> setprio(1) 32 MFMA setprio(0).
//  - WAR safe: stage(t+1) overwrites the buffer whose reads all waves completed before
//    passing this tile's top barrier (their lgkmcnt(0) precedes the barrier in prog order).
// Step map (HAS_U): t 0-3 xf@Wut^T (relu'd at t=3), 4-7 xc@Wc^T, 8-11 xf@Wu^T, 12-27 z@U^T.
template<bool HAS_U, bool WRITE_F32>
__global__ __launch_bounds__(256, 2)
void icnn_layer_kernel(const short* __restrict__ xc, const short* __restrict__ xf,
                       const short* __restrict__ zin,
                       const short* __restrict__ Wc, const short* __restrict__ Wu,
                       const short* __restrict__ Wut, const short* __restrict__ U,
                       const float* __restrict__ bc, const float* __restrict__ bu,
                       const float* __restrict__ but,
                       __hip_bfloat16* __restrict__ zout, float* __restrict__ fout)
{
    __shared__ short lds_s[4][128 * 64];   // [0],[1]=A bufs; [2],[3]=B bufs; 64KB
    const int t_ = threadIdx.x;            // 0..255
    const int lane = t_ & 63;
    const int wid = t_ >> 6;               // 0..3
    const int wr = wid >> 1, wc = wid & 1; // 2x2 wave grid; 64x64 per wave
    const int l15 = lane & 15, l4 = lane >> 4;
    const int swz = l15 & 7;               // == row&7 for every fragment row this lane reads
    const int brow = blockIdx.x * 128;
    const int bcol = blockIdx.y * 128;

    constexpr int NSTEP = HAS_U ? 28 : 12;

    f32x4 acc[4][4];
#pragma unroll
    for (int m = 0; m < 4; ++m)
#pragma unroll
        for (int n = 0; n < 4; ++n) acc[m][n] = (f32x4){0.f, 0.f, 0.f, 0.f};

    float bt[4];
#pragma unroll
    for (int n = 0; n < 4; ++n) bt[n] = but[bcol + wc * 64 + n * 16 + l15];

    // resolve operands for step s; ld as shift (256 -> 8, 1024 -> 10)
    auto seg = [&](int s, const short*& A, int& lsa, const short*& B, int& lsb, int& k0) {
        if (s < 4)       { A = xf;  lsa = 8;  B = Wut; lsb = 8;  k0 = s * 64; }
        else if (s < 8)  { A = xc;  lsa = 8;  B = Wc;  lsb = 8;  k0 = (s - 4) * 64; }
        else if (s < 12) { A = xf;  lsa = 8;  B = Wu;  lsb = 8;  k0 = (s - 8) * 64; }
        else             { A = zin; lsa = 10; B = U;   lsb = 10; k0 = (s - 12) * 64; }
    };

    // stage tile for step s; LDS dest linear, source column-chunk XOR-swizzled.
    // A 128x64 = 1024 16B-chunks / 256 thr = 4 each; B same. 8 loads/thread.
    auto stage = [&](short* Ad, short* Bd, int s) {
        const short *Ag, *Bg; int lsa, lsb, k0;
        seg(s, Ag, lsa, Bg, lsb, k0);
#pragma unroll
        for (int it = 0; it < 4; ++it) {
            int c = it * 256 + t_;
            int row = c >> 3;                 // 8 chunks per 64-elem row
            int js = (c & 7) ^ (row & 7);     // inverse swizzle on source
            GLOAD16(Ag + (((size_t)(brow + row)) << lsa) + k0 + js * 8, Ad + c * 8);
        }
#pragma unroll
        for (int it = 0; it < 4; ++it) {
            int c = it * 256 + t_;
            int row = c >> 3;
            int js = (c & 7) ^ (row & 7);
            GLOAD16(Bg + (((size_t)(bcol + row)) << lsb) + k0 + js * 8, Bd + c * 8);
        }
    };

    auto tile = [&](const short* As, const short* Bs, short* An, short* Bn, int t) {
        // stage(t) was issued one full tile ago -> this wait is nearly free
        asm volatile("s_waitcnt vmcnt(0)" ::: "memory");
        __builtin_amdgcn_s_barrier();

        // fragment base addresses (bytes); row stride 128B, col-chunk XOR-swizzled
        const uint32_t abase = lds_addr32(As) + ((uint32_t)(wr * 64 + l15) << 7);
        const uint32_t bbase = lds_addr32(Bs) + ((uint32_t)(wc * 64 + l15) << 7);
        const uint32_t a0 = abase + (uint32_t)((l4 ^ swz) << 4);
        const uint32_t a1 = abase + (uint32_t)(((4 + l4) ^ swz) << 4);
        const uint32_t b0 = bbase + (uint32_t)((l4 ^ swz) << 4);
        const uint32_t b1 = bbase + (uint32_t)(((4 + l4) ^ swz) << 4);

        short8 a[2][4], b[2][4];
        DSREAD(a[0][0], a0, 0);    DSREAD(a[0][1], a0, 2048);
        DSREAD(a[0][2], a0, 4096); DSREAD(a[0][3], a0, 6144);
        DSREAD(b[0][0], b0, 0);    DSREAD(b[0][1], b0, 2048);
        DSREAD(b[0][2], b0, 4096); DSREAD(b[0][3], b0, 6144);
        DSREAD(a[1][0], a1, 0);    DSREAD(a[1][1], a1, 2048);
        DSREAD(a[1][2], a1, 4096); DSREAD(a[1][3], a1, 6144);
        DSREAD(b[1][0], b1, 0);    DSREAD(b[1][1], b1, 2048);
        DSREAD(b[1][2], b1, 4096); DSREAD(b[1][3], b1, 6144);

        // next tile's DMA: a full tile (~1400cyc) to land before its vmcnt(0)
        if (t + 1 < NSTEP) stage(An, Bn, t + 1);

        asm volatile("s_waitcnt lgkmcnt(0)" ::: "memory");
        __builtin_amdgcn_sched_barrier(0);   // rule 18: MFMA must not hoist above the wait

        __builtin_amdgcn_s_setprio(1);
#pragma unroll
        for (int kk = 0; kk < 2; ++kk)
#pragma unroll
            for (int m = 0; m < 4; ++m)
#pragma unroll
                for (int n = 0; n < 4; ++n)
                    acc[m][n] = __builtin_amdgcn_mfma_f32_16x16x32_bf16(a[kk][m], b[kk][n], acc[m][n], 0, 0, 0);
        __builtin_amdgcn_s_setprio(0);

        if (t == 3) {
            // u = relu(xf@Wut^T + but); MFMA accumulates the remaining paths on top
#pragma unroll
            for (int n = 0; n < 4; ++n)
#pragma unroll
                for (int m = 0; m < 4; ++m)
#pragma unroll
                    for (int v = 0; v < 4; ++v)
                        acc[m][n][v] = fmaxf(acc[m][n][v] + bt[n], 0.f);
        }
    };

    // ---- prologue ----
    stage(lds_s[0], lds_s[2], 0);

    // ---- main loop: buffer identity compile-time via x2 unroll (NSTEP even) ----
    for (int i = 0; i < NSTEP / 2; ++i) {
        tile(lds_s[0], lds_s[2], lds_s[1], lds_s[3], 2 * i);
        tile(lds_s[1], lds_s[3], lds_s[0], lds_s[2], 2 * i + 1);
    }

    // ---- epilogue: + (bc + bu), relu, store ----
    float bb[4];
#pragma unroll
    for (int n = 0; n < 4; ++n) {
        int col = bcol + wc * 64 + n * 16 + l15;
        bb[n] = bc[col] + bu[col];
    }

    if constexpr (WRITE_F32) {
        // f32: 16 consecutive lanes cover one full 64B line -> direct store
#pragma unroll
        for (int n = 0; n < 4; ++n) {
            int col = bcol + wc * 64 + n * 16 + l15;
#pragma unroll
            for (int m = 0; m < 4; ++m) {
                int row = brow + wr * 64 + m * 16 + l4 * 4;
#pragma unroll
                for (int v = 0; v < 4; ++v)
                    fout[(size_t)(row + v) * 1024 + col] = fmaxf(acc[m][n][v] + bb[n], 0.f);
            }
        }
    } else {
        // bf16: bounce via LDS (64KB = 128x128 f32) for full-line 64B global writes
        __syncthreads();   // all DMA drained (last tile waited vmcnt(0)); all frag reads done
        float* fs = (float*)&lds_s[0][0];
#pragma unroll
        for (int n = 0; n < 4; ++n) {
            int col = wc * 64 + n * 16 + l15;
#pragma unroll
            for (int m = 0; m < 4; ++m) {
                int row = wr * 64 + m * 16 + l4 * 4;
#pragma unroll
                for (int v = 0; v < 4; ++v)
                    fs[(row + v) * 128 + col] = fmaxf(acc[m][n][v] + bb[n], 0.f);
            }
        }
        __syncthreads();
        const int rrow = t_ >> 5;          // 0..7
        const int rcol = (t_ & 31) * 4;    // 0..124
#pragma unroll
        for (int p = 0; p < 16; ++p) {
            int row = p * 8 + rrow;
            float4 v4 = *(const float4*)&fs[row * 128 + rcol];
            ushort4 o;
            o.x = __bfloat16_as_ushort(__float2bfloat16(v4.x));
            o.y = __bfloat16_as_ushort(__float2bfloat16(v4.y));
            o.z = __bfloat16_as_ushort(__float2bfloat16(v4.z));
            o.w = __bfloat16_as_ushort(__float2bfloat16(v4.w));
            *(ushort4*)&zout[(size_t)(brow + row) * 1024 + bcol + rcol] = o;
        }
    }
}

extern "C" void kernel_launch(void* const* d_in, const int* in_sizes, int n_in,
                              void* d_out, int out_size, void* d_ws, size_t ws_size,
                              hipStream_t stream)
{
    const float* xc    = (const float*)d_in[0];
    const float* xf    = (const float*)d_in[1];
    const float* Wc_w  = (const float*)d_in[2];
    const float* Wc_b  = (const float*)d_in[3];
    const float* Wu_w  = (const float*)d_in[4];
    const float* Wu_b  = (const float*)d_in[5];
    const float* Wut_w = (const float*)d_in[6];
    const float* Wut_b = (const float*)d_in[7];
    const float* raw_U = (const float*)d_in[8];

    // workspace layout (bf16 buffers), ~36 MB total
    short* p = (short*)d_ws;
    short* xc_bf  = p; p += 8192 * 256;
    short* xf_bf  = p; p += 8192 * 256;
    short* Wc_bf  = p; p += 4 * 1024 * 256;
    short* Wu_bf  = p; p += 4 * 1024 * 256;
    short* Wut_bf = p; p += 4 * 1024 * 256;
    short* U_bf   = p; p += 3 * 1024 * 1024;
    short* z_a    = p; p += 8192 * 1024;
    // z_b lives in d_out (bf16 scratch); layer 3 fully overwrites d_out with fp32 result.
    short* z_b = (short*)d_out;

    xform_all<<<dim3(10240), dim3(256), 0, stream>>>(
        xc, xf, Wc_w, Wu_w, Wut_w, raw_U,
        xc_bf, xf_bf, Wc_bf, Wu_bf, Wut_bf, U_bf);

    dim3 tb(256);
    dim3 grid(8192 / 128, 1024 / 128);   // 64 x 8 = 512 blocks = 2/CU
    const int WS = 1024 * 256;
    const int US = 1024 * 1024;

    // layer 0 (no recurrence) -> z_a
    icnn_layer_kernel<false, false><<<grid, tb, 0, stream>>>(
        xc_bf, xf_bf, nullptr, Wc_bf, Wu_bf, Wut_bf, nullptr,
        Wc_b, Wu_b, Wut_b, (__hip_bfloat16*)z_a, nullptr);
    // layer 1 -> z_b (in d_out)
    icnn_layer_kernel<true, false><<<grid, tb, 0, stream>>>(
        xc_bf, xf_bf, z_a, Wc_bf + WS, Wu_bf + WS, Wut_bf + WS, U_bf,
        Wc_b + 1024, Wu_b + 1024, Wut_b + 1024, (__hip_bfloat16*)z_b, nullptr);
    // layer 2 -> z_a
    icnn_layer_kernel<true, false><<<grid, tb, 0, stream>>>(
        xc_bf, xf_bf, z_b, Wc_bf + 2 * WS, Wu_bf + 2 * WS, Wut_bf + 2 * WS, U_bf + US,
        Wc_b + 2048, Wu_b + 2048, Wut_b + 2048, (__hip_bfloat16*)z_a, nullptr);
    // layer 3 -> fp32 d_out
    icnn_layer_kernel<true, true><<<grid, tb, 0, stream>>>(
        xc_bf, xf_bf, z_a, Wc_bf + 3 * WS, Wu_bf + 3 * WS, Wut_bf + 3 * WS, U_bf + 2 * US,
        Wc_b + 3072, Wu_b + 3072, Wut_b + 3072, nullptr, (float*)d_out);
}